// Round 7
// baseline (142.833 us; speedup 1.0000x reference)
//
#include <hip/hip_runtime.h>
#include <math.h>

#define DIM 4096
#define NRF 8192
#define NV4  (DIM / 4)            // 1024 float4 per row
#define TPB  256                  // 4 waves/block, 1 row per wave
#define NBLK (NRF / 4)            // 2048 blocks

typedef float f32x4 __attribute__((ext_vector_type(4)));

// k_main: pure streaming, zero LDS, zero syncthreads. Wave w of block b owns
// rf row = b*4+w. Lane reads gs_x/gs_w row slices (coalesced 16B) and the
// matching x/w slices from global (32 KB working set -> L1-resident after the
// first touch; L1 has ~3x the needed port BW). ||x||^2+||w||^2 is fused into
// the same loop: each lane touches every x/w element exactly once across its
// 16 iterations, so sq accumulates for free. One shuffle chain reduces the
// dot and sq together; lane 0 writes exp() to partials[row].
// R2-R6 established: delivered BW caps at ~6.3 TB/s regardless of L3
// residency (fabric ingress), fences are catastrophic, two plain dispatches
// beat memset+atomic tails. This just deletes the non-streaming prologue.
__global__ __launch_bounds__(TPB, 8) void k_main(const f32x4* __restrict__ gsx,
                                                 const f32x4* __restrict__ gsw,
                                                 const float* __restrict__ xis,
                                                 const f32x4* __restrict__ x4,
                                                 const f32x4* __restrict__ w4,
                                                 float* __restrict__ partials) {
    int t    = threadIdx.x;
    int lane = t & 63;
    int wid  = t >> 6;

    int row = blockIdx.x * 4 + wid;
    const f32x4* __restrict__ rx = gsx + (size_t)row * NV4;
    const f32x4* __restrict__ rw = gsw + (size_t)row * NV4;

    float dx0 = 0.f, dx1 = 0.f, dw0 = 0.f, dw1 = 0.f;
    float sq0 = 0.f, sq1 = 0.f;
    #pragma unroll
    for (int k = 0; k < NV4 / 64; k += 2) {        // 8 unrolled iters, 2-way ILP
        f32x4 a = rx[k * 64 + lane];
        f32x4 b = x4[k * 64 + lane];
        dx0 += a.x*b.x + a.y*b.y + a.z*b.z + a.w*b.w;
        sq0 += b.x*b.x + b.y*b.y + b.z*b.z + b.w*b.w;
        f32x4 c = rx[(k + 1) * 64 + lane];
        f32x4 d = x4[(k + 1) * 64 + lane];
        dx1 += c.x*d.x + c.y*d.y + c.z*d.z + c.w*d.w;
        sq1 += d.x*d.x + d.y*d.y + d.z*d.z + d.w*d.w;
        f32x4 e = rw[k * 64 + lane];
        f32x4 f = w4[k * 64 + lane];
        dw0 += e.x*f.x + e.y*f.y + e.z*f.z + e.w*f.w;
        sq0 += f.x*f.x + f.y*f.y + f.z*f.z + f.w*f.w;
        f32x4 g = rw[(k + 1) * 64 + lane];
        f32x4 h = w4[(k + 1) * 64 + lane];
        dw1 += g.x*h.x + g.y*h.y + g.z*h.z + g.w*h.w;
        sq1 += h.x*h.x + h.y*h.y + h.z*h.z + h.w*h.w;
    }
    float s = (dx0 + dx1) + (dw0 + dw1);
    float q = sq0 + sq1;
    #pragma unroll
    for (int off = 32; off >= 1; off >>= 1) {
        s += __shfl_xor(s, off);
        q += __shfl_xor(q, off);
    }

    if (lane == 0) {
        float xi = xis[row];
        float e  = xi * s - 0.5f * xi * xi * q;
        partials[row] = expf(e);
    }
}

// k_reduce: sum 8192 f32 partials (vectorized), f64 accumulate, scale, store.
__global__ __launch_bounds__(256) void k_reduce(const f32x4* __restrict__ partials,
                                                float* __restrict__ out) {
    int t = threadIdx.x;
    double a = 0.0;
    #pragma unroll
    for (int i = 0; i < (NRF / 4) / 256; ++i) {    // 8 vec4 per thread
        f32x4 v = partials[t + i * 256];
        a += (double)v.x + (double)v.y + (double)v.z + (double)v.w;
    }
    #pragma unroll
    for (int off = 32; off >= 1; off >>= 1) a += __shfl_xor(a, off);
    __shared__ double s[4];
    if ((t & 63) == 0) s[t >> 6] = a;
    __syncthreads();
    if (t == 0) out[0] = (float)((s[0] + s[1] + s[2] + s[3]) * (1.0 / (double)NRF));
}

extern "C" void kernel_launch(void* const* d_in, const int* in_sizes, int n_in,
                              void* d_out, int out_size, void* d_ws, size_t ws_size,
                              hipStream_t stream) {
    const float* x    = (const float*)d_in[0];   // [4096]
    const float* w    = (const float*)d_in[1];   // [4096]
    const float* xis  = (const float*)d_in[2];   // [8192]
    const f32x4* gsx  = (const f32x4*)d_in[3];   // [8192,4096]
    const f32x4* gsw  = (const f32x4*)d_in[4];   // [8192,4096]
    float* out = (float*)d_out;

    float* partials = (float*)d_ws;              // [NRF] per-row exp values

    k_main<<<NBLK, TPB, 0, stream>>>(gsx, gsw, xis,
                                     (const f32x4*)x, (const f32x4*)w, partials);
    k_reduce<<<1, 256, 0, stream>>>((const f32x4*)partials, out);
}

// Round 8
// 47.665 us; speedup vs baseline: 2.9966x; 2.9966x over previous
//
#include <hip/hip_runtime.h>
#include <math.h>

#define DIM 4096
#define NRF 8192
#define NBLK 1024
#define TPB  512
#define NV4  (DIM / 4)        // 1024 float4 per row
#define ROWS_PER_BLOCK 8      // 8 waves/block, 1 row-pair per wave

// R2 config, reverted verbatim (measured 48.1 us, best of R0-R7):
//  - per-BLOCK LDS staging of x/w (32 KB): amortizes the hot-line x/w reads
//    1024x instead of 8192x (R7 showed per-wave global re-reads collapse to
//    1.8 TB/s via L2 hot-line contention);
//  - cached loads (R3: nontemporal hints regress -- delivered BW caps at
//    ~6.3 TB/s regardless of L3 residency);
//  - plain two-dispatch reduce (R5: fences catastrophic; R6: memset+atomic
//    costs more than a second tiny kernel);
//  - k_main delivers 268 MB at ~6.1 TB/s = 97% of the measured copy ceiling.
__global__ __launch_bounds__(TPB, 4) void k_main(const float4* __restrict__ gsx,
                                                 const float4* __restrict__ gsw,
                                                 const float*  __restrict__ xis,
                                                 const float4* __restrict__ x4,
                                                 const float4* __restrict__ w4,
                                                 float* __restrict__ partials) {
    __shared__ float4 lx[NV4];
    __shared__ float4 lw[NV4];
    __shared__ float  ssq_s[8];
    __shared__ float  wsum[8];

    int t = threadIdx.x;
    int lane = t & 63;
    int wid  = t >> 6;

    // Stage x, w into LDS (each thread moves 2 float4 of each).
    float4 a0 = x4[t], a1 = x4[t + TPB];
    float4 b0 = w4[t], b1 = w4[t + TPB];
    lx[t] = a0; lx[t + TPB] = a1;
    lw[t] = b0; lw[t + TPB] = b1;

    // Fused ||x||^2 + ||w||^2 from the registers we just staged.
    float ssq = a0.x*a0.x + a0.y*a0.y + a0.z*a0.z + a0.w*a0.w
              + a1.x*a1.x + a1.y*a1.y + a1.z*a1.z + a1.w*a1.w
              + b0.x*b0.x + b0.y*b0.y + b0.z*b0.z + b0.w*b0.w
              + b1.x*b1.x + b1.y*b1.y + b1.z*b1.z + b1.w*b1.w;
    #pragma unroll
    for (int off = 32; off >= 1; off >>= 1) ssq += __shfl_xor(ssq, off);
    if (lane == 0) ssq_s[wid] = ssq;
    __syncthreads();
    float sxw = ssq_s[0] + ssq_s[1] + ssq_s[2] + ssq_s[3]
              + ssq_s[4] + ssq_s[5] + ssq_s[6] + ssq_s[7];

    // One row per wave.
    int row = blockIdx.x * ROWS_PER_BLOCK + wid;
    const float4* __restrict__ rx = gsx + (size_t)row * NV4;
    const float4* __restrict__ rw = gsw + (size_t)row * NV4;

    float dx0 = 0.f, dx1 = 0.f, dw0 = 0.f, dw1 = 0.f;
    #pragma unroll
    for (int k = 0; k < NV4 / 64; k += 2) {        // 16 iters, 2-way ILP
        float4 a = rx[k * 64 + lane];
        float4 b = lx[k * 64 + lane];
        dx0 += a.x*b.x + a.y*b.y + a.z*b.z + a.w*b.w;
        float4 c = rx[(k + 1) * 64 + lane];
        float4 d = lx[(k + 1) * 64 + lane];
        dx1 += c.x*d.x + c.y*d.y + c.z*d.z + c.w*d.w;
        float4 e = rw[k * 64 + lane];
        float4 f = lw[k * 64 + lane];
        dw0 += e.x*f.x + e.y*f.y + e.z*f.z + e.w*f.w;
        float4 g = rw[(k + 1) * 64 + lane];
        float4 h = lw[(k + 1) * 64 + lane];
        dw1 += g.x*h.x + g.y*h.y + g.z*h.z + g.w*h.w;
    }
    float s = (dx0 + dx1) + (dw0 + dw1);
    #pragma unroll
    for (int off = 32; off >= 1; off >>= 1) s += __shfl_xor(s, off);

    if (lane == 0) {
        float xi = xis[row];
        float e  = xi * s - 0.5f * xi * xi * sxw;
        wsum[wid] = expf(e);
    }
    __syncthreads();
    if (t == 0) {
        partials[blockIdx.x] = wsum[0] + wsum[1] + wsum[2] + wsum[3]
                             + wsum[4] + wsum[5] + wsum[6] + wsum[7];
    }
}

// Final reduce: f64 accumulate of 1024 f32 partials, scale, store.
__global__ __launch_bounds__(256) void k_reduce(const float* __restrict__ partials,
                                                float* __restrict__ out) {
    int t = threadIdx.x;
    double a = 0.0;
    for (int i = t; i < NBLK; i += 256) a += (double)partials[i];
    #pragma unroll
    for (int off = 32; off >= 1; off >>= 1) a += __shfl_xor(a, off);
    __shared__ double s[4];
    if ((t & 63) == 0) s[t >> 6] = a;
    __syncthreads();
    if (t == 0) out[0] = (float)((s[0] + s[1] + s[2] + s[3]) * (1.0 / (double)NRF));
}

extern "C" void kernel_launch(void* const* d_in, const int* in_sizes, int n_in,
                              void* d_out, int out_size, void* d_ws, size_t ws_size,
                              hipStream_t stream) {
    const float* x    = (const float*)d_in[0];   // [4096]
    const float* w    = (const float*)d_in[1];   // [4096]
    const float* xis  = (const float*)d_in[2];   // [8192]
    const float4* gsx = (const float4*)d_in[3];  // [8192,4096]
    const float4* gsw = (const float4*)d_in[4];  // [8192,4096]
    float* out = (float*)d_out;

    float* par = (float*)d_ws;                   // [NBLK] partials

    k_main<<<NBLK, TPB, 0, stream>>>(gsx, gsw, xis,
                                     (const float4*)x, (const float4*)w, par);
    k_reduce<<<1, 256, 0, stream>>>(par, out);
}